// Round 18
// baseline (179.180 us; speedup 1.0000x reference)
//
#include <hip/hip_runtime.h>
#include <math.h>

// Problem dims (fixed)
#define BB 4
#define TT 1024
#define CC 1024
#define HH 16
#define DD 64
#define NQKV (3 * CC)      // 3072
#define MROWS (BB * TT)    // 4096

typedef __attribute__((ext_vector_type(8))) short bf16x8;   // 8 bf16 (4 VGPRs)
typedef __attribute__((ext_vector_type(4))) float f32x4;    // MFMA C/D

struct alignas(8) US4 { unsigned short x, y, z, w; };

__device__ __forceinline__ float b2f(unsigned short u) {
  unsigned int w = ((unsigned int)u) << 16;
  float f; __builtin_memcpy(&f, &w, 4); return f;
}
__device__ __forceinline__ unsigned short f2b(float f) {
  unsigned int u; __builtin_memcpy(&u, &f, 4);
  u += 0x7FFFu + ((u >> 16) & 1);        // RNE
  return (unsigned short)(u >> 16);
}

// raw hardware transcendentals: v_log_f32 (log2), v_exp_f32 (2^x)
__device__ __forceinline__ float hw_log2(float x) {
  return __builtin_amdgcn_logf(x);
}
__device__ __forceinline__ float hw_exp2(float x) {
  return __builtin_amdgcn_exp2f(x);
}

// async global->LDS, 16 B per lane; lds dest is wave-uniform base + lane*16
__device__ __forceinline__ void gload16(const void* g, void* l) {
  __builtin_amdgcn_global_load_lds(
      (const __attribute__((address_space(1))) unsigned int*)g,
      (__attribute__((address_space(3))) unsigned int*)l, 16, 0, 0);
}

// swizzled frag read: row_base points at a 128-B LDS row; logical 16-B chunk
// lc is stored at physical chunk lc ^ (row & 7).
__device__ __forceinline__ bf16x8 ld_sw(const unsigned short* row_base,
                                        int lc, int rsw) {
  return *(const bf16x8*)((const char*)row_base + (((lc ^ rsw) & 7) << 4));
}

// ---------------------------------------------------------------------------
// PREP (verified r13): one launch = W_qkv transpose | W_out transpose |
// spike flags + x->bf16.
// ---------------------------------------------------------------------------
__global__ __launch_bounds__(256) void prep(
    const float* __restrict__ x, const float* __restrict__ w_sur,
    const float* __restrict__ b_sur, const float* __restrict__ thr,
    const float* __restrict__ W_qkv, const float* __restrict__ W_out,
    float* __restrict__ spikes, unsigned short* __restrict__ xb,
    unsigned short* __restrict__ WqkvT, unsigned short* __restrict__ WoutT) {
  __shared__ float t[32][33];
  const int blk = blockIdx.x;

  if (blk < 4096) {
    const float* W; unsigned short* WT; int K, N, bx, by;
    if (blk < 3072) {
      W = W_qkv; WT = WqkvT; K = CC; N = NQKV;
      bx = blk % 96; by = blk / 96;
    } else {
      W = W_out; WT = WoutT; K = CC; N = CC;
      const int b2 = blk - 3072;
      bx = b2 & 31; by = b2 >> 5;
    }
    const int tx = threadIdx.x & 31, ty = threadIdx.x >> 5;
    const int k0 = by * 32, n0 = bx * 32;
#pragma unroll
    for (int i = 0; i < 32; i += 8)
      t[ty + i][tx] = W[(size_t)(k0 + ty + i) * N + n0 + tx];
    __syncthreads();
#pragma unroll
    for (int i = 0; i < 32; i += 8)
      WT[(size_t)(n0 + ty + i) * K + k0 + tx] = f2b(t[tx][ty + i]);
  } else {
    const int row = (blk - 4096) * 4 + (threadIdx.x >> 6);
    const int lane = threadIdx.x & 63;
    const float* xr = x + (size_t)row * CC;
    unsigned short* xo = xb + (size_t)row * CC;
    double acc = 0.0;
#pragma unroll
    for (int s = 0; s < 4; ++s) {
      const int idx = s * 256 + lane * 4;
      const float4 xv = *(const float4*)(xr + idx);
      const float4 wv = *(const float4*)(w_sur + idx);
      acc += (double)xv.x * (double)wv.x;
      acc += (double)xv.y * (double)wv.y;
      acc += (double)xv.z * (double)wv.z;
      acc += (double)xv.w * (double)wv.w;
      US4 o = {f2b(xv.x), f2b(xv.y), f2b(xv.z), f2b(xv.w)};
      *(US4*)(xo + idx) = o;
    }
#pragma unroll
    for (int off = 32; off > 0; off >>= 1) acc += __shfl_xor(acc, off, 64);
    if (lane == 0) {
      const float z = (float)acc + b_sur[0];
      const float imp = 1.0f / (1.0f + __expf(-z));
      spikes[row] = (imp > thr[0]) ? 1.0f : 0.0f;
    }
  }
}

// ---------------------------------------------------------------------------
// QKV GEMM + fused Lorentz + fused V-transpose. r18: 256x64 tiles, 8 waves
// (512 thr). Per-wave code identical to verified r15 (32 rows x 64 cols,
// same frags/swizzle/epilogue); geometry halves blocks 1536->768 (3/CU,
// 24 waves/CU unchanged) => barrier-drain events per CU halve (96->48) and
// each barrier has 2x independent MFMA work to overlap the drain.
// LDS: staging As 256x64 (32 KB) + Bs 64x64 (8 KB) = 40 KB; epilogue reuses
// 32 KB as 8 x 4 KB per-wave scratch.
// ---------------------------------------------------------------------------
__global__ __launch_bounds__(512) void gemm_qkv(
    const unsigned short* __restrict__ A, const unsigned short* __restrict__ BT,
    const float* __restrict__ bias, unsigned short* __restrict__ qkvb,
    unsigned short* __restrict__ vT) {
  const int K = CC;
  __shared__ unsigned short SH[20480];     // 40 KB: As 256x64 | Bs 64x64
  unsigned short (*As)[64] = (unsigned short(*)[64])SH;
  unsigned short (*Bs)[64] = (unsigned short(*)[64])(SH + 16384);
  const int tid = threadIdx.x;
  const int lane = tid & 63;
  const int wave = tid >> 6;           // 0..7
  const int wm = wave * 32;            // wave's first row (0..224)
  const int m0 = blockIdx.y * 256;
  const int n0 = blockIdx.x * 64;
  const int ln15 = lane & 15;
  const int g = lane >> 4;
  const int rsw = ln15 & 7;            // frag-read swizzle key

  const int srow = tid >> 3;           // 0..63
  const int schk = ((tid & 7) ^ (srow & 7)) * 8;   // swizzled fetch chunk
  const unsigned short* gA = A + (size_t)(m0 + srow) * K + schk;
  const unsigned short* gB = BT + (size_t)(n0 + srow) * K + schk;
  char* lA = (char*)SH + wave * 1024;            // wave covers rows w*8..+7
  char* lB = (char*)SH + 32768 + wave * 1024;    // Bs base

  f32x4 acc[2][4] = {};

  for (int k0 = 0; k0 < K; k0 += 64) {
    __syncthreads();
#pragma unroll
    for (int i = 0; i < 4; ++i)        // A: 4 x 64 rows
      gload16(gA + k0 + (size_t)(64 * i) * K, lA + i * 8192);
    gload16(gB + k0, lB);              // B: 64 rows in one issue
    __syncthreads();

#pragma unroll
    for (int c = 0; c < 2; ++c) {
      bf16x8 af[2], bfr[4];
#pragma unroll
      for (int i = 0; i < 2; ++i)
        af[i] = ld_sw(&As[wm + i * 16 + ln15][0], c * 4 + g, rsw);
#pragma unroll
      for (int j = 0; j < 4; ++j)
        bfr[j] = ld_sw(&Bs[j * 16 + ln15][0], c * 4 + g, rsw);
#pragma unroll
      for (int i = 0; i < 2; ++i)
#pragma unroll
        for (int j = 0; j < 4; ++j)
          acc[i][j] = __builtin_amdgcn_mfma_f32_16x16x32_bf16(
              af[i], bfr[j], acc[i][j], 0, 0, 0);
    }
  }

  __syncthreads();                       // all MFMA frag reads done
  unsigned short* scr = SH + wave * 2048;  // per-wave 32x64 scratch (4 KB)

  const int bx = blockIdx.x;             // segment id: q<16, k<32, v else
  if (bx < 32) {
    const bool isk = (bx >= 16);
#pragma unroll
    for (int i = 0; i < 2; ++i) {
#pragma unroll
      for (int r = 0; r < 4; ++r) {
        float u[4];
        float part = 0.f;
#pragma unroll
        for (int j = 0; j < 4; ++j) {
          u[j] = acc[i][j][r] + bias[n0 + j * 16 + ln15];
          float sq = u[j] * u[j];
          if (j == 0 && ln15 == 0) sq = -sq;     // time component
          part += sq;
        }
#pragma unroll
        for (int off = 1; off < 16; off <<= 1)
          part += __shfl_xor(part, off, 64);
        const float nomin = sqrtf(fmaxf(part, 1e-8f));
        const float e = __expf(nomin);
        const float ei = __builtin_amdgcn_rcpf(e);
        const float tim = 0.5f * (e + ei);
        const float coef = 0.5f * (e - ei) * __builtin_amdgcn_rcpf(nomin);
        const int lrow = i * 16 + g * 4 + r;     // token-local 0..31
#pragma unroll
        for (int j = 0; j < 4; ++j) {
          float o = (j == 0 && ln15 == 0) ? tim : coef * u[j];
          if (isk && !(j == 0 && ln15 == 0)) o = -o;
          const int col = j * 16 + ln15;
          const int ch = ((col >> 3) + lrow) & 7;
          scr[lrow * 64 + ch * 8 + (col & 7)] = f2b(o);
        }
      }
    }
#pragma unroll
    for (int it = 0; it < 4; ++it) {
      const int row = (lane >> 3) + 8 * it;    // 0..31
      const int ch = lane & 7;
      const int ph = (ch + row) & 7;
      const bf16x8 v = *(const bf16x8*)&scr[row * 64 + ph * 8];
      *(bf16x8*)&qkvb[(size_t)(m0 + wm + row) * NQKV + n0 + ch * 8] = v;
    }
  } else {
#pragma unroll
    for (int i = 0; i < 2; ++i) {
#pragma unroll
      for (int j = 0; j < 4; ++j) {
        const float bb_ = bias[n0 + j * 16 + ln15];
        const int drow = j * 16 + ln15;          // 0..63
#pragma unroll
        for (int r = 0; r < 4; ++r) {
          const int col = i * 16 + g * 4 + r;    // t-local 0..31
          const int ch = ((col >> 3) + drow) & 3;
          scr[drow * 32 + ch * 8 + (col & 7)] = f2b(acc[i][j][r] + bb_);
        }
      }
    }
    const int hh = bx - 32;
    const int mbase = m0 + wm;
    const int bq = mbase >> 10;
    const int t0 = mbase & 1023;
#pragma unroll
    for (int it = 0; it < 4; ++it) {
      const int drow = (lane >> 2) + 16 * it;  // 0..63
      const int ch = lane & 3;
      const int ph = (ch + drow) & 3;
      const bf16x8 v = *(const bf16x8*)&scr[drow * 32 + ph * 8];
      *(bf16x8*)&vT[((size_t)(bq * HH + hh) * DD + drow) * TT + t0 + ch * 8] = v;
    }
  }
}

// ---------------------------------------------------------------------------
// Out GEMM (verified r15): 128x64 tiles, 2/CU, XOR chunk swizzle.
// ---------------------------------------------------------------------------
__global__ __launch_bounds__(256) void gemm_out(
    const unsigned short* __restrict__ A, const unsigned short* __restrict__ BT,
    const float* __restrict__ bias, float* __restrict__ C) {
  const int N = CC, K = CC;
  __shared__ unsigned short As[128][64];   // 16 KB
  __shared__ unsigned short Bs[64][64];    // 8 KB
  const int tid = threadIdx.x;
  const int lane = tid & 63;
  const int wave = tid >> 6;
  const int wm = wave * 32;
  const int m0 = blockIdx.y * 128;
  const int n0 = blockIdx.x * 64;
  const int ln15 = lane & 15;
  const int g = lane >> 4;
  const int rsw = ln15 & 7;

  const int srow = tid >> 3;           // 0..31
  const int schk = ((tid & 7) ^ (srow & 7)) * 8;
  const unsigned short* gA = A + (size_t)(m0 + srow) * K + schk;
  const unsigned short* gB = BT + (size_t)(n0 + srow) * K + schk;
  char* lA = (char*)As + wave * 1024;
  char* lB = (char*)Bs + wave * 1024;

  f32x4 acc[2][4] = {};

  for (int k0 = 0; k0 < K; k0 += 64) {
    __syncthreads();
#pragma unroll
    for (int i = 0; i < 4; ++i)
      gload16(gA + k0 + (size_t)(32 * i) * K, lA + i * 4096);
#pragma unroll
    for (int i = 0; i < 2; ++i)
      gload16(gB + k0 + (size_t)(32 * i) * K, lB + i * 4096);
    __syncthreads();

#pragma unroll
    for (int c = 0; c < 2; ++c) {
      bf16x8 af[2], bfr[4];
#pragma unroll
      for (int i = 0; i < 2; ++i)
        af[i] = ld_sw(&As[wm + i * 16 + ln15][0], c * 4 + g, rsw);
#pragma unroll
      for (int j = 0; j < 4; ++j)
        bfr[j] = ld_sw(&Bs[j * 16 + ln15][0], c * 4 + g, rsw);
#pragma unroll
      for (int i = 0; i < 2; ++i)
#pragma unroll
        for (int j = 0; j < 4; ++j)
          acc[i][j] = __builtin_amdgcn_mfma_f32_16x16x32_bf16(
              af[i], bfr[j], acc[i][j], 0, 0, 0);
    }
  }

#pragma unroll
  for (int i = 0; i < 2; ++i) {
#pragma unroll
    for (int r = 0; r < 4; ++r) {
      const int m = m0 + wm + i * 16 + g * 4 + r;
#pragma unroll
      for (int j = 0; j < 4; ++j) {
        const int n = n0 + j * 16 + ln15;
        C[(size_t)m * N + n] = acc[i][j][r] + bias[n];
      }
    }
  }
}

// ---------------------------------------------------------------------------
// MFMA flash, 128-row Q blocks (verified r17): 128-col KV iterations,
// hw log2/exp2 transform, unmasked fast path, balanced pairing.
// ---------------------------------------------------------------------------
__global__ __launch_bounds__(512) void flash_mfma(
    const unsigned short* __restrict__ qkv, const unsigned short* __restrict__ vT,
    const float* __restrict__ spikes, unsigned short* __restrict__ y) {
  __shared__ unsigned short Ks[128][68];
  __shared__ unsigned short Vs[64][136];   // Vs[d][t-local 0..127]
  __shared__ unsigned short Ps[128][68];

  const int tid = threadIdx.x;
  const int lane = tid & 63;
  const int wave = tid >> 6;              // 0..7
  const int ln15 = lane & 15;
  const int g = lane >> 4;
  const int bh = blockIdx.y;
  const int itile = (bh < 32) ? ((int)gridDim.x - 1 - (int)blockIdx.x)
                              : (int)blockIdx.x;   // balanced pairing
  const int b = bh >> 4;
  const int h = bh & 15;
  const int i0 = itile * 128;
  const int band = wave * 16;
  const int htiles = itile + 1;           // 128-col iterations
  const unsigned short* base = qkv + (size_t)b * TT * NQKV;
  const unsigned short* vbase = vT + (size_t)bh * DD * TT;  // rows d, cols t
  const int qoff = h * DD;
  const int koff = CC + h * DD;

  // staging coords
  const int ksn = tid >> 2;            // K row 0..127
  const int kqc = (tid & 3) * 2;       // two 16-B chunks of the 128-B row
  const int vsn = tid >> 3;            // V d-row 0..63
  const int vqc = (tid & 7) * 2;       // two 16-B chunks of the 256-B row

  bf16x8 qf[2];
  {
    const unsigned short* qp = base + (size_t)(i0 + band + ln15) * NQKV + qoff;
    qf[0] = *(const bf16x8*)(qp + g * 8);
    qf[1] = *(const bf16x8*)(qp + 32 + g * 8);
  }

  f32x4 accy[4] = {};           // y[m=g*4+r][d=dt*16+ln15] (unnormalized)
  float lrow[4] = {0.f, 0.f, 0.f, 0.f};

  // prefetch iteration 0
  float4 kr0, kr1, vr0, vr1;
  {
    const unsigned short* kp = base + (size_t)ksn * NQKV + koff + kqc * 8;
    const unsigned short* vp = vbase + (size_t)vsn * TT + vqc * 8;
    kr0 = *(const float4*)(kp + 0);
    kr1 = *(const float4*)(kp + 8);
    vr0 = *(const float4*)(vp + 0);
    vr1 = *(const float4*)(vp + 8);
  }

  for (int ht = 0; ht < htiles; ++ht) {
    const int j0h = ht * 128;
    __syncthreads();                       // prior-iter Ks/Vs consumers done
    *(float4*)&Ks[ksn][kqc * 8 + 0] = kr0;
    *(float4*)&Ks[ksn][kqc * 8 + 8] = kr1;
    *(float4*)&Vs[vsn][vqc * 8 + 0] = vr0;
    *(float4*)&Vs[vsn][vqc * 8 + 8] = vr1;
    __syncthreads();

    // prefetch next iteration (overlaps with compute below)
    if (ht + 1 < htiles) {
      const int j1 = j0h + 128;
      const unsigned short* kp = base + (size_t)(j1 + ksn) * NQKV + koff + kqc * 8;
      const unsigned short* vp = vbase + (size_t)vsn * TT + j1 + vqc * 8;
      kr0 = *(const float4*)(kp + 0);
      kr1 = *(const float4*)(kp + 8);
      vr0 = *(const float4*)(vp + 0);
      vr1 = *(const float4*)(vp + 8);
    }

#pragma unroll
    for (int t2 = 0; t2 < 2; ++t2) {
      const int j0 = j0h + t2 * 64;
      if (j0 > i0 + band + 15) continue;   // fully masked for this band

      // S = Q . K^T  (K rows t2*64 .. +63)
      f32x4 sf[4];
#pragma unroll
      for (int j = 0; j < 4; ++j) {
        const bf16x8 k0 = *(const bf16x8*)&Ks[t2 * 64 + j * 16 + ln15][g * 8];
        const bf16x8 k1 = *(const bf16x8*)&Ks[t2 * 64 + j * 16 + ln15][32 + g * 8];
        f32x4 z = {};
        z = __builtin_amdgcn_mfma_f32_16x16x32_bf16(qf[0], k0, z, 0, 0, 0);
        sf[j] = __builtin_amdgcn_mfma_f32_16x16x32_bf16(qf[1], k1, z, 0, 0, 0);
      }

      // p = exp2(-(ln2/8) * (log2(z)+1)^2);  ln2/8 = 0.08664339757
      float p[4][4];
      if (j0 + 63 <= i0 + band) {
#pragma unroll
        for (int j = 0; j < 4; ++j)
#pragma unroll
          for (int r = 0; r < 4; ++r) {
            const float l = hw_log2(fmaxf(sf[j][r], 1.0f));
            const float s = l + 1.0f;
            p[r][j] = hw_exp2(-0.08664339757f * s * s);
          }
      } else {
#pragma unroll
        for (int j = 0; j < 4; ++j) {
          const int gj = j0 + j * 16 + ln15;
#pragma unroll
          for (int r = 0; r < 4; ++r) {
            const int gi = i0 + band + g * 4 + r;
            float e;
            if (gj > gi) {
              e = 0.f;
            } else {
              const float l = hw_log2(fmaxf(sf[j][r], 1.0f));
              const float s = l + 1.0f;
              e = hw_exp2(-0.08664339757f * s * s);
            }
            p[r][j] = e;
          }
        }
      }
#pragma unroll
      for (int r = 0; r < 4; ++r)
        lrow[r] += (p[r][0] + p[r][1]) + (p[r][2] + p[r][3]);

      // P -> LDS (bf16, A-layout); intra-wave producer/consumer, no barrier
#pragma unroll
      for (int r = 0; r < 4; ++r)
#pragma unroll
        for (int j = 0; j < 4; ++j)
          Ps[band + g * 4 + r][j * 16 + ln15] = f2b(p[r][j]);

      const bf16x8 pa0 = *(const bf16x8*)&Ps[band + ln15][g * 8];
      const bf16x8 pa1 = *(const bf16x8*)&Ps[band + ln15][32 + g * 8];
#pragma unroll
      for (int dt = 0; dt < 4; ++dt) {
        const bf16x8 v0 = *(const bf16x8*)&Vs[dt * 16 + ln15][t2 * 64 + g * 8];
        const bf16x8 v1 = *(const bf16x8*)&Vs[dt * 16 + ln15][t2 * 64 + 32 + g * 8];
        accy[dt] = __builtin_amdgcn_mfma_f32_16x16x32_bf16(pa0, v0, accy[dt], 0, 0, 0);
        accy[dt] = __builtin_amdgcn_mfma_f32_16x16x32_bf16(pa1, v1, accy[dt], 0, 0, 0);
      }
    }
  }

  // epilogue: reduce lrow across the 16 n-lanes, scale, store
#pragma unroll
  for (int r = 0; r < 4; ++r) {
#pragma unroll
    for (int off = 1; off < 16; off <<= 1)
      lrow[r] += __shfl_xor(lrow[r], off, 64);
  }
  const int grow = b * TT + i0 + band + g * 4;
#pragma unroll
  for (int r = 0; r < 4; ++r) {
    const float spk = spikes[grow + r];
    const float scale = spk / lrow[r];
#pragma unroll
    for (int dt = 0; dt < 4; ++dt)
      y[(size_t)(grow + r) * CC + h * DD + dt * 16 + ln15] =
          f2b(accy[dt][r] * scale);
  }
}

// ---------------------------------------------------------------------------
extern "C" void kernel_launch(void* const* d_in, const int* in_sizes, int n_in,
                              void* d_out, int out_size, void* d_ws, size_t ws_size,
                              hipStream_t stream) {
  const float* x     = (const float*)d_in[0];
  const float* W_qkv = (const float*)d_in[1];
  const float* b_qkv = (const float*)d_in[2];
  const float* W_out = (const float*)d_in[3];
  const float* b_out = (const float*)d_in[4];
  const float* w_sur = (const float*)d_in[5];
  const float* b_sur = (const float*)d_in[6];
  const float* thr   = (const float*)d_in[7];
  float* out = (float*)d_out;

  // ws layout (bytes, total ~58.8 MB):
  //   xb 8.39M | qkvb 25.17M | vT 8.39M | ybufb 8.39M | WqkvT 6.29M |
  //   WoutT 2.10M | spikes 16K
  char* w = (char*)d_ws;
  unsigned short* xb    = (unsigned short*)(w);
  unsigned short* qkvb  = (unsigned short*)(w + 8388608);
  unsigned short* vTb   = (unsigned short*)(w + 8388608 + 25165824);
  unsigned short* ybufb = (unsigned short*)(w + 8388608 + 25165824 + 8388608);
  unsigned short* WqkvT = (unsigned short*)(w + 8388608 + 25165824 + 2 * 8388608);
  unsigned short* WoutT = (unsigned short*)(w + 8388608 + 25165824 + 2 * 8388608 + 6291456);
  float* spikes = (float*)(w + 8388608 + 25165824 + 2 * 8388608 + 6291456 + 2097152);

  prep<<<5120, 256, 0, stream>>>(x, w_sur, b_sur, thr, W_qkv, W_out,
                                 spikes, xb, WqkvT, WoutT);

  // 256x64 tiles: 768 blocks = 3/CU x 8 waves (drain events halved)
  gemm_qkv<<<dim3(NQKV / 64, MROWS / 256), 512, 0, stream>>>(
      xb, WqkvT, b_qkv, qkvb, vTb);

  flash_mfma<<<dim3(TT / 128, BB * HH), 512, 0, stream>>>(qkvb, vTb, spikes, ybufb);

  gemm_out<<<dim3(CC / 64, MROWS / 128), 256, 0, stream>>>(
      ybufb, WoutT, b_out, out);
}